// Round 1
// baseline (8457.029 us; speedup 1.0000x reference)
//
#include <hip/hip_runtime.h>
#include <hip/hip_bf16.h>
#include <math.h>

#define NN 100000
#define E_RAW 1600000
#define E_TOT 1700000
#define HEADS 8
#define CH 16
#define FDIM 128
#define NCLS 40
#define SLOPE 0.2f

__device__ __forceinline__ void atomicMaxF(float* addr, float val) {
    if (val >= 0.f) atomicMax((int*)addr, __float_as_int(val));
    else            atomicMin((unsigned int*)addr, __float_as_uint(val));
}

// ---------------- GEMM: [NN,128] @ [128,128] -> [NN,128] ----------------
__global__ __launch_bounds__(256) void gemm128(const float* __restrict__ X,
                                               const float* __restrict__ Wm,
                                               float* __restrict__ Out) {
    __shared__ float xs[16][132];
    const int col = threadIdx.x & 127;
    const int grp = threadIdx.x >> 7;   // 0..1
    const int row0 = blockIdx.x << 4;   // 16 rows/block, 100000 % 16 == 0
    for (int i = threadIdx.x; i < 2048; i += 256) {
        int r = i >> 7, k = i & 127;
        xs[r][k] = X[(row0 + r) * 128 + k];
    }
    __syncthreads();
    float acc[8] = {0.f,0.f,0.f,0.f,0.f,0.f,0.f,0.f};
    const float* wp = Wm + col;
    for (int k = 0; k < 128; k += 4) {
        float w0 = wp[(k+0)*128], w1 = wp[(k+1)*128];
        float w2 = wp[(k+2)*128], w3 = wp[(k+3)*128];
        #pragma unroll
        for (int j = 0; j < 8; ++j) {
            const float4 xv = *(const float4*)&xs[grp*8 + j][k];
            float a = acc[j];
            a = fmaf(xv.x, w0, a); a = fmaf(xv.y, w1, a);
            a = fmaf(xv.z, w2, a); a = fmaf(xv.w, w3, a);
            acc[j] = a;
        }
    }
    #pragma unroll
    for (int j = 0; j < 8; ++j)
        Out[(row0 + grp*8 + j) * 128 + col] = acc[j];
}

// ---------------- per-node attention coefficients ----------------
__global__ __launch_bounds__(256) void alar_kernel(const float* __restrict__ Hm,
                                                   const float* __restrict__ attl,
                                                   const float* __restrict__ attr,
                                                   float* __restrict__ AL,
                                                   float* __restrict__ AR) {
    int idx = blockIdx.x * 256 + threadIdx.x;   // idx = n*8 + hd
    if (idx >= NN * HEADS) return;
    int hd = idx & 7;
    const float4* hp = (const float4*)(Hm + (long)(idx >> 3) * 128 + hd * 16);
    const float4* lp = (const float4*)(attl + hd * 16);
    const float4* rp = (const float4*)(attr + hd * 16);
    float sl = 0.f, sr = 0.f;
    #pragma unroll
    for (int q = 0; q < 4; ++q) {
        float4 h4 = hp[q], l4 = lp[q], r4 = rp[q];
        sl = fmaf(h4.x,l4.x, fmaf(h4.y,l4.y, fmaf(h4.z,l4.z, fmaf(h4.w,l4.w, sl))));
        sr = fmaf(h4.x,r4.x, fmaf(h4.y,r4.y, fmaf(h4.z,r4.z, fmaf(h4.w,r4.w, sr))));
    }
    AL[idx] = sl; AR[idx] = sr;
}

// ---------------- init accumulators for one layer ----------------
__global__ __launch_bounds__(256) void init_layer(float* __restrict__ M,
                                                  float* __restrict__ DEN,
                                                  float* __restrict__ ACC) {
    int i = blockIdx.x * 256 + threadIdx.x;
    if (i < NN * 128) ACC[i] = 0.f;
    if (i < NN * HEADS) { M[i] = -INFINITY; DEN[i] = 0.f; }
}

// ---------------- edge pass A: segment max (mask NOT applied, per reference) --
__global__ __launch_bounds__(256) void edge_max(const int* __restrict__ src_a,
                                                const int* __restrict__ dst_a,
                                                const float* __restrict__ AL,
                                                const float* __restrict__ AR,
                                                float* __restrict__ M) {
    int e = blockIdx.x * 256 + threadIdx.x;
    if (e >= E_TOT) return;
    int s, d;
    if (e < E_RAW) { s = src_a[e]; d = dst_a[e]; }
    else           { s = d = e - E_RAW; }
    #pragma unroll
    for (int hd = 0; hd < HEADS; ++hd) {
        float ev = AL[s*8 + hd] + AR[d*8 + hd];
        ev = ev > 0.f ? ev : SLOPE * ev;
        atomicMaxF(&M[d*8 + hd], ev);
    }
}

// ---------------- edge pass B: softmax denominator ----------------
__global__ __launch_bounds__(256) void edge_denom(const int* __restrict__ src_a,
                                                  const int* __restrict__ dst_a,
                                                  const float* __restrict__ AL,
                                                  const float* __restrict__ AR,
                                                  const float* __restrict__ M,
                                                  float* __restrict__ DEN) {
    int e = blockIdx.x * 256 + threadIdx.x;
    if (e >= E_TOT) return;
    int s, d;
    if (e < E_RAW) { s = src_a[e]; d = dst_a[e]; if (s == d) return; }
    else           { s = d = e - E_RAW; }
    #pragma unroll
    for (int hd = 0; hd < HEADS; ++hd) {
        float ev = AL[s*8 + hd] + AR[d*8 + hd];
        ev = ev > 0.f ? ev : SLOPE * ev;
        float ex = expf(ev - M[d*8 + hd]);
        atomicAdd(&DEN[d*8 + hd], ex);
    }
}

// ---------------- edge pass C: alpha-weighted message scatter ----------------
// 32 lanes per edge, 4 features each (one head per lane-quad group of 4 feats)
__global__ __launch_bounds__(256) void edge_msg(const int* __restrict__ src_a,
                                                const int* __restrict__ dst_a,
                                                const float* __restrict__ AL,
                                                const float* __restrict__ AR,
                                                const float* __restrict__ M,
                                                const float* __restrict__ DEN,
                                                const float* __restrict__ Hm,
                                                float* __restrict__ ACC) {
    int t = blockIdx.x * 256 + threadIdx.x;
    int e = t >> 5;
    if (e >= E_TOT) return;
    int lane = t & 31;
    int s, d;
    if (e < E_RAW) { s = src_a[e]; d = dst_a[e]; if (s == d) return; }
    else           { s = d = e - E_RAW; }
    int hd = lane >> 2;  // 4 lanes per head, 4 feats per lane
    float ev = AL[s*8 + hd] + AR[d*8 + hd];
    ev = ev > 0.f ? ev : SLOPE * ev;
    float ex = expf(ev - M[d*8 + hd]);
    float alpha = ex / fmaxf(DEN[d*8 + hd], 1e-16f);
    const float4 hv = *(const float4*)(Hm + (long)s * 128 + lane * 4);
    float* ap = ACC + (long)d * 128 + lane * 4;
    atomicAdd(ap + 0, hv.x * alpha);
    atomicAdd(ap + 1, hv.y * alpha);
    atomicAdd(ap + 2, hv.z * alpha);
    atomicAdd(ap + 3, hv.w * alpha);
}

// ---------------- bias + ELU (in place) ----------------
__global__ __launch_bounds__(256) void bias_elu(float* __restrict__ A,
                                                const float* __restrict__ b) {
    int i = blockIdx.x * 256 + threadIdx.x;
    if (i >= NN * 128) return;
    float v = A[i] + b[i & 127];
    A[i] = v > 0.f ? v : expm1f(v);
}

// ---------------- classifier: [NN,128] @ [128,40] + bc ----------------
__global__ __launch_bounds__(256) void classifier(const float* __restrict__ X,
                                                  const float* __restrict__ Wc,
                                                  const float* __restrict__ bc,
                                                  float* __restrict__ Out) {
    __shared__ float ws[128 * NCLS];   // 20KB
    __shared__ float xs[32][132];      // 16.9KB
    for (int i = threadIdx.x; i < 128 * NCLS; i += 256) ws[i] = Wc[i];
    const int row0 = blockIdx.x << 5;  // 32 rows/block, 100000 % 32 == 0
    for (int i = threadIdx.x; i < 32 * 128; i += 256) {
        int r = i >> 7, k = i & 127;
        xs[r][k] = X[(row0 + r) * 128 + k];
    }
    __syncthreads();
    const int r  = threadIdx.x >> 3;        // 0..31
    const int c0 = (threadIdx.x & 7) * 5;   // 0,5,...,35
    float acc[5] = {0.f,0.f,0.f,0.f,0.f};
    for (int k = 0; k < 128; ++k) {
        float xv = xs[r][k];
        #pragma unroll
        for (int j = 0; j < 5; ++j)
            acc[j] = fmaf(xv, ws[k * NCLS + c0 + j], acc[j]);
    }
    #pragma unroll
    for (int j = 0; j < 5; ++j)
        Out[(row0 + r) * NCLS + c0 + j] = acc[j] + bc[c0 + j];
}

extern "C" void kernel_launch(void* const* d_in, const int* in_sizes, int n_in,
                              void* d_out, int out_size, void* d_ws, size_t ws_size,
                              hipStream_t stream) {
    const float* x    = (const float*)d_in[0];
    const int*   ei   = (const int*)  d_in[1];
    // d_in[2] edge_weight: unused (matches reference)
    const float* W1   = (const float*)d_in[3];
    const float* al1  = (const float*)d_in[4];
    const float* ar1  = (const float*)d_in[5];
    const float* b1   = (const float*)d_in[6];
    const float* W2   = (const float*)d_in[7];
    const float* al2  = (const float*)d_in[8];
    const float* ar2  = (const float*)d_in[9];
    const float* b2   = (const float*)d_in[10];
    const float* Wc   = (const float*)d_in[11];
    const float* bc   = (const float*)d_in[12];
    float* out = (float*)d_out;

    const int* src = ei;
    const int* dst = ei + E_RAW;

    char* ws = (char*)d_ws;
    float* h   = (float*)(ws);                        // 51.2 MB
    float* acc = (float*)(ws + 51200000);             // 51.2 MB
    float* AL  = (float*)(ws + 102400000);            // 3.2 MB
    float* AR  = AL + NN * HEADS;                     // 3.2 MB
    float* M   = AR + NN * HEADS;                     // 3.2 MB
    float* DEN = M  + NN * HEADS;                     // 3.2 MB  (total ~115 MB)

    const int gRows16  = NN / 16;                     // 6250
    const int gNodeH   = (NN * HEADS + 255) / 256;    // 3125
    const int gInit    = (NN * 128 + 255) / 256;      // 50000
    const int gEdge    = (E_TOT + 255) / 256;         // 6641
    const int gMsg     = (E_TOT * 32 + 255) / 256;    // 212500
    const int gElem    = (NN * 128 + 255) / 256;      // 50000
    const int gCls     = NN / 32;                     // 3125

    // ---- layer 1 ----
    gemm128<<<gRows16, 256, 0, stream>>>(x, W1, h);
    alar_kernel<<<gNodeH, 256, 0, stream>>>(h, al1, ar1, AL, AR);
    init_layer<<<gInit, 256, 0, stream>>>(M, DEN, acc);
    edge_max<<<gEdge, 256, 0, stream>>>(src, dst, AL, AR, M);
    edge_denom<<<gEdge, 256, 0, stream>>>(src, dst, AL, AR, M, DEN);
    edge_msg<<<gMsg, 256, 0, stream>>>(src, dst, AL, AR, M, DEN, h, acc);
    bias_elu<<<gElem, 256, 0, stream>>>(acc, b1);

    // ---- layer 2 (h buffer reused; acc reused after gemm consumes it) ----
    gemm128<<<gRows16, 256, 0, stream>>>(acc, W2, h);
    alar_kernel<<<gNodeH, 256, 0, stream>>>(h, al2, ar2, AL, AR);
    init_layer<<<gInit, 256, 0, stream>>>(M, DEN, acc);
    edge_max<<<gEdge, 256, 0, stream>>>(src, dst, AL, AR, M);
    edge_denom<<<gEdge, 256, 0, stream>>>(src, dst, AL, AR, M, DEN);
    edge_msg<<<gMsg, 256, 0, stream>>>(src, dst, AL, AR, M, DEN, h, acc);
    bias_elu<<<gElem, 256, 0, stream>>>(acc, b2);

    // ---- classifier ----
    classifier<<<gCls, 256, 0, stream>>>(acc, Wc, bc, out);
}

// Round 3
// 989.353 us; speedup vs baseline: 8.5480x; 8.5480x over previous
//
#include <hip/hip_runtime.h>
#include <hip/hip_bf16.h>
#include <math.h>

#define NN 100000
#define E_RAW 1600000
#define E_TOT 1700000
#define HEADS 8
#define CH 16
#define FDIM 128
#define NCLS 40
#define SLOPE 0.2f

// ================= GEMM: [NN,128] @ [128,128] -> [NN,128] =================
__global__ __launch_bounds__(256) void gemm128(const float* __restrict__ X,
                                               const float* __restrict__ Wm,
                                               float* __restrict__ Out) {
    __shared__ float xs[16][132];
    const int col = threadIdx.x & 127;
    const int grp = threadIdx.x >> 7;   // 0..1
    const int row0 = blockIdx.x << 4;   // 16 rows/block, 100000 % 16 == 0
    for (int i = threadIdx.x; i < 2048; i += 256) {
        int r = i >> 7, k = i & 127;
        xs[r][k] = X[(row0 + r) * 128 + k];
    }
    __syncthreads();
    float acc[8] = {0.f,0.f,0.f,0.f,0.f,0.f,0.f,0.f};
    const float* wp = Wm + col;
    for (int k = 0; k < 128; k += 4) {
        float w0 = wp[(k+0)*128], w1 = wp[(k+1)*128];
        float w2 = wp[(k+2)*128], w3 = wp[(k+3)*128];
        #pragma unroll
        for (int j = 0; j < 8; ++j) {
            const float4 xv = *(const float4*)&xs[grp*8 + j][k];
            float a = acc[j];
            a = fmaf(xv.x, w0, a); a = fmaf(xv.y, w1, a);
            a = fmaf(xv.z, w2, a); a = fmaf(xv.w, w3, a);
            acc[j] = a;
        }
    }
    #pragma unroll
    for (int j = 0; j < 8; ++j)
        Out[(row0 + grp*8 + j) * 128 + col] = acc[j];
}

// ================= per-node attention coefficients =================
__global__ __launch_bounds__(256) void alar_kernel(const float* __restrict__ Hm,
                                                   const float* __restrict__ attl,
                                                   const float* __restrict__ attr,
                                                   float* __restrict__ AL,
                                                   float* __restrict__ AR) {
    int idx = blockIdx.x * 256 + threadIdx.x;   // idx = n*8 + hd
    if (idx >= NN * HEADS) return;
    int hd = idx & 7;
    const float4* hp = (const float4*)(Hm + (long)(idx >> 3) * 128 + hd * 16);
    const float4* lp = (const float4*)(attl + hd * 16);
    const float4* rp = (const float4*)(attr + hd * 16);
    float sl = 0.f, sr = 0.f;
    #pragma unroll
    for (int q = 0; q < 4; ++q) {
        float4 h4 = hp[q], l4 = lp[q], r4 = rp[q];
        sl = fmaf(h4.x,l4.x, fmaf(h4.y,l4.y, fmaf(h4.z,l4.z, fmaf(h4.w,l4.w, sl))));
        sr = fmaf(h4.x,r4.x, fmaf(h4.y,r4.y, fmaf(h4.z,r4.z, fmaf(h4.w,r4.w, sr))));
    }
    AL[idx] = sl; AR[idx] = sr;
}

// ================= CSR build =================
// cnt[n] starts at 1 (the appended self-loop per node)
__global__ __launch_bounds__(256) void csr_init_cnt(int* __restrict__ cnt) {
    int i = blockIdx.x * 256 + threadIdx.x;
    if (i < NN) cnt[i] = 1;
}

__global__ __launch_bounds__(256) void csr_hist(const int* __restrict__ dst_a,
                                                int* __restrict__ cnt) {
    int e = blockIdx.x * 256 + threadIdx.x;
    if (e < E_RAW) atomicAdd(&cnt[dst_a[e]], 1);
}

// block-level exclusive scan (256 per block), emits block sums
__global__ __launch_bounds__(256) void scan_block(const int* __restrict__ cnt,
                                                  int* __restrict__ part,
                                                  int* __restrict__ bsum) {
    __shared__ int s[256];
    int i = blockIdx.x * 256 + threadIdx.x;
    int v = (i < NN) ? cnt[i] : 0;
    s[threadIdx.x] = v;
    __syncthreads();
    for (int off = 1; off < 256; off <<= 1) {
        int t = (threadIdx.x >= off) ? s[threadIdx.x - off] : 0;
        __syncthreads();
        s[threadIdx.x] += t;
        __syncthreads();
    }
    if (i < NN) part[i] = s[threadIdx.x] - v;   // exclusive within block
    if (threadIdx.x == 255) bsum[blockIdx.x] = s[255];
}

// single-block exclusive scan of 391 block sums
__global__ __launch_bounds__(512) void scan_partials(int* __restrict__ bsum, int nb) {
    __shared__ int s[512];
    int v = (threadIdx.x < nb) ? bsum[threadIdx.x] : 0;
    s[threadIdx.x] = v;
    __syncthreads();
    for (int off = 1; off < 512; off <<= 1) {
        int t = (threadIdx.x >= off) ? s[threadIdx.x - off] : 0;
        __syncthreads();
        s[threadIdx.x] += t;
        __syncthreads();
    }
    if (threadIdx.x < nb) bsum[threadIdx.x] = s[threadIdx.x] - v;  // exclusive
}

__global__ __launch_bounds__(256) void scan_add(const int* __restrict__ part,
                                                const int* __restrict__ bsum,
                                                int* __restrict__ roff,
                                                int* __restrict__ rpos) {
    int i = blockIdx.x * 256 + threadIdx.x;
    if (i < NN) {
        int v = part[i] + bsum[blockIdx.x];
        roff[i] = v; rpos[i] = v;
    }
    if (i == NN) roff[NN] = E_TOT;
}

// scatter edges into CSR; bit31 flags masked (raw self-loop dup) edges
__global__ __launch_bounds__(256) void csr_scatter(const int* __restrict__ src_a,
                                                   const int* __restrict__ dst_a,
                                                   int* __restrict__ rpos,
                                                   int* __restrict__ csr) {
    int e = blockIdx.x * 256 + threadIdx.x;
    if (e >= E_TOT) return;
    int s, d, flag;
    if (e < E_RAW) { s = src_a[e]; d = dst_a[e]; flag = (s == d); }
    else           { s = d = e - E_RAW; flag = 0; }
    int pos = atomicAdd(&rpos[d], 1);
    csr[pos] = s | (flag << 31);
}

// ================= fused GAT layer: softmax + gather + bias + ELU =========
// one wave (64 lanes) per destination node; 4 waves per block
__global__ __launch_bounds__(256) void gat_fused(const int* __restrict__ roff,
                                                 const int* __restrict__ csr,
                                                 const float* __restrict__ AL,
                                                 const float* __restrict__ AR,
                                                 const float* __restrict__ Hm,
                                                 const float* __restrict__ bias,
                                                 float* __restrict__ Out) {
    const int lane = threadIdx.x & 63;
    const int n = blockIdx.x * 4 + (threadIdx.x >> 6);
    const int hd = lane >> 3;      // 8 lanes per head
    const int t  = lane & 7;
    const int r0 = roff[n], r1 = roff[n + 1];
    const float ard = AR[n * 8 + hd];

    // pass 1: segment max over ALL edges (masked dups included, per reference)
    float mx = -INFINITY;
    for (int j = r0 + t; j < r1; j += 8) {
        int sw = csr[j];
        int s = sw & 0x7fffffff;
        float ev = AL[s * 8 + hd] + ard;
        ev = ev > 0.f ? ev : SLOPE * ev;
        mx = fmaxf(mx, ev);
    }
    mx = fmaxf(mx, __shfl_xor(mx, 1));
    mx = fmaxf(mx, __shfl_xor(mx, 2));
    mx = fmaxf(mx, __shfl_xor(mx, 4));
    mx = isfinite(mx) ? mx : 0.f;

    // pass 2: softmax denominator (masked edges excluded)
    float den = 0.f;
    for (int j = r0 + t; j < r1; j += 8) {
        int sw = csr[j];
        int s = sw & 0x7fffffff;
        float msk = (sw >= 0) ? 1.f : 0.f;
        float ev = AL[s * 8 + hd] + ard;
        ev = ev > 0.f ? ev : SLOPE * ev;
        den = fmaf(msk, expf(ev - mx), den);
    }
    den += __shfl_xor(den, 1);
    den += __shfl_xor(den, 2);
    den += __shfl_xor(den, 4);
    const float inv = 1.f / fmaxf(den, 1e-16f);

    // pass 3: alpha-weighted gather-accumulate (lane covers feats 2l, 2l+1;
    // head of feat 2l is (2l)>>4 == lane>>3 == hd, so mx/inv already match)
    float a0 = 0.f, a1 = 0.f;
    for (int j = r0; j < r1; ++j) {
        int sw = csr[j];                 // same for all lanes -> broadcast
        int s = sw & 0x7fffffff;
        float msk = (sw >= 0) ? 1.f : 0.f;
        float ev = AL[s * 8 + hd] + ard;
        ev = ev > 0.f ? ev : SLOPE * ev;
        float alpha = expf(ev - mx) * inv * msk;
        float2 hv = *(const float2*)(Hm + (size_t)s * 128 + lane * 2);
        a0 = fmaf(hv.x, alpha, a0);
        a1 = fmaf(hv.y, alpha, a1);
    }
    a0 += bias[lane * 2];
    a1 += bias[lane * 2 + 1];
    a0 = a0 > 0.f ? a0 : expm1f(a0);
    a1 = a1 > 0.f ? a1 : expm1f(a1);
    *(float2*)(Out + (size_t)n * 128 + lane * 2) = make_float2(a0, a1);
}

// ================= classifier: [NN,128] @ [128,40] + bc =================
__global__ __launch_bounds__(256) void classifier(const float* __restrict__ X,
                                                  const float* __restrict__ Wc,
                                                  const float* __restrict__ bc,
                                                  float* __restrict__ Out) {
    __shared__ float ws[128 * NCLS];   // 20KB
    __shared__ float xs[32][132];      // 16.9KB
    for (int i = threadIdx.x; i < 128 * NCLS; i += 256) ws[i] = Wc[i];
    const int row0 = blockIdx.x << 5;  // 32 rows/block
    for (int i = threadIdx.x; i < 32 * 128; i += 256) {
        int r = i >> 7, k = i & 127;
        xs[r][k] = X[(row0 + r) * 128 + k];
    }
    __syncthreads();
    const int r  = threadIdx.x >> 3;        // 0..31
    const int c0 = (threadIdx.x & 7) * 5;   // 0,5,...,35
    float acc[5] = {0.f,0.f,0.f,0.f,0.f};
    for (int k = 0; k < 128; ++k) {
        float xv = xs[r][k];
        #pragma unroll
        for (int j = 0; j < 5; ++j)
            acc[j] = fmaf(xv, ws[k * NCLS + c0 + j], acc[j]);
    }
    #pragma unroll
    for (int j = 0; j < 5; ++j)
        Out[(row0 + r) * NCLS + c0 + j] = acc[j] + bc[c0 + j];
}

extern "C" void kernel_launch(void* const* d_in, const int* in_sizes, int n_in,
                              void* d_out, int out_size, void* d_ws, size_t ws_size,
                              hipStream_t stream) {
    const float* x    = (const float*)d_in[0];
    const int*   ei   = (const int*)  d_in[1];
    // d_in[2] edge_weight: unused (matches reference)
    const float* W1   = (const float*)d_in[3];
    const float* al1  = (const float*)d_in[4];
    const float* ar1  = (const float*)d_in[5];
    const float* b1   = (const float*)d_in[6];
    const float* W2   = (const float*)d_in[7];
    const float* al2  = (const float*)d_in[8];
    const float* ar2  = (const float*)d_in[9];
    const float* b2   = (const float*)d_in[10];
    const float* Wc   = (const float*)d_in[11];
    const float* bc   = (const float*)d_in[12];
    float* out = (float*)d_out;

    const int* src = ei;
    const int* dst = ei + E_RAW;

    char* ws = (char*)d_ws;
    float* h    = (float*)(ws);                        // 51.2 MB
    float* acc  = (float*)(ws + 51200000UL);           // 51.2 MB
    float* AL   = (float*)(ws + 102400000UL);          // 3.2 MB
    float* AR   = (float*)(ws + 105600000UL);          // 3.2 MB
    int*   csr  = (int*)  (ws + 108800000UL);          // 6.8 MB
    int*   cnt  = (int*)  (ws + 115600000UL);          // 0.4 MB
    int*   roff = (int*)  (ws + 116000000UL);          // 0.4 MB (+4)
    int*   rpos = (int*)  (ws + 116400004UL);          // 0.4 MB
    int*   part = (int*)  (ws + 116800004UL);          // 0.4 MB
    int*   bsum = (int*)  (ws + 117200004UL);          // 2 KB

    const int NB_N   = (NN + 255) / 256;               // 391
    const int gRaw   = (E_RAW + 255) / 256;            // 6250
    const int gTot   = (E_TOT + 255) / 256;            // 6641
    const int gRows16 = NN / 16;                       // 6250
    const int gNodeH  = (NN * HEADS + 255) / 256;      // 3125
    const int gGat    = NN / 4;                        // 25000
    const int gCls    = NN / 32;                       // 3125

    // ---- CSR build (shared by both layers) ----
    csr_init_cnt<<<NB_N, 256, 0, stream>>>(cnt);
    csr_hist<<<gRaw, 256, 0, stream>>>(dst, cnt);
    scan_block<<<NB_N, 256, 0, stream>>>(cnt, part, bsum);
    scan_partials<<<1, 512, 0, stream>>>(bsum, NB_N);
    scan_add<<<NB_N, 256, 0, stream>>>(part, bsum, roff, rpos);
    csr_scatter<<<gTot, 256, 0, stream>>>(src, dst, rpos, csr);

    // ---- layer 1 ----
    gemm128<<<gRows16, 256, 0, stream>>>(x, W1, h);
    alar_kernel<<<gNodeH, 256, 0, stream>>>(h, al1, ar1, AL, AR);
    gat_fused<<<gGat, 256, 0, stream>>>(roff, csr, AL, AR, h, b1, acc);

    // ---- layer 2 ----
    gemm128<<<gRows16, 256, 0, stream>>>(acc, W2, h);
    alar_kernel<<<gNodeH, 256, 0, stream>>>(h, al2, ar2, AL, AR);
    gat_fused<<<gGat, 256, 0, stream>>>(roff, csr, AL, AR, h, b2, acc);

    // ---- classifier ----
    classifier<<<gCls, 256, 0, stream>>>(acc, Wc, bc, out);
}

// Round 6
// 904.346 us; speedup vs baseline: 9.3515x; 1.0940x over previous
//
#include <hip/hip_runtime.h>
#include <hip/hip_bf16.h>
#include <math.h>

#define NN 100000
#define E_RAW 1600000
#define E_TOT 1700000
#define HEADS 8
#define CH 16
#define FDIM 128
#define NCLS 40
#define SLOPE 0.2f

// ========== GEMM [NN,128]@[128,128] + fused AL/AR epilogue ==========
// 32 rows/block, 256 thr = 128 cols x 2 grps, 16 accs/thread
__global__ __launch_bounds__(256) void gemm128_alar(const float* __restrict__ X,
                                                    const float* __restrict__ Wm,
                                                    const float* __restrict__ attl,
                                                    const float* __restrict__ attr,
                                                    float* __restrict__ Out,
                                                    float* __restrict__ AL,
                                                    float* __restrict__ AR) {
    __shared__ float xs[32][132];
    const int col = threadIdx.x & 127;
    const int grp = threadIdx.x >> 7;     // 0..1 -> rows grp*16..+15
    const int row0 = blockIdx.x << 5;     // 32 rows/block, 100000 % 32 == 0
    for (int i = threadIdx.x; i < 32 * 128; i += 256) {
        int r = i >> 7, k = i & 127;
        xs[r][k] = X[(size_t)(row0 + r) * 128 + k];
    }
    __syncthreads();
    float acc[16];
    #pragma unroll
    for (int r = 0; r < 16; ++r) acc[r] = 0.f;
    const float* wp = Wm + col;
    for (int k = 0; k < 128; k += 4) {
        float w0 = wp[(k+0)*128], w1 = wp[(k+1)*128];
        float w2 = wp[(k+2)*128], w3 = wp[(k+3)*128];
        #pragma unroll
        for (int r = 0; r < 16; ++r) {
            const float4 xv = *(const float4*)&xs[grp*16 + r][k];
            float a = acc[r];
            a = fmaf(xv.x, w0, a); a = fmaf(xv.y, w1, a);
            a = fmaf(xv.z, w2, a); a = fmaf(xv.w, w3, a);
            acc[r] = a;
        }
    }
    #pragma unroll
    for (int r = 0; r < 16; ++r)
        Out[(size_t)(row0 + grp*16 + r) * 128 + col] = acc[r];

    // ---- fused AL/AR: al[n,hd] = sum_{c in head} h[n,c]*attl[c] ----
    const float lw = attl[col], rw = attr[col];
    const int hd = col >> 4;
    #pragma unroll
    for (int r = 0; r < 16; ++r) {
        float pl = acc[r] * lw;
        float pr = acc[r] * rw;
        #pragma unroll
        for (int off = 1; off < 16; off <<= 1) {
            pl += __shfl_xor(pl, off);
            pr += __shfl_xor(pr, off);
        }
        if ((col & 15) == 0) {
            int n = row0 + grp*16 + r;
            AL[n*8 + hd] = pl;
            AR[n*8 + hd] = pr;
        }
    }
}

// ================= CSR build =================
__global__ __launch_bounds__(256) void csr_init_cnt(int* __restrict__ cnt) {
    int i = blockIdx.x * 256 + threadIdx.x;
    if (i < NN) cnt[i] = 1;   // self-loop
}

__global__ __launch_bounds__(256) void csr_hist(const int* __restrict__ dst_a,
                                                int* __restrict__ cnt) {
    int e = blockIdx.x * 256 + threadIdx.x;
    if (e < E_RAW) atomicAdd(&cnt[dst_a[e]], 1);
}

__global__ __launch_bounds__(256) void scan_block(const int* __restrict__ cnt,
                                                  int* __restrict__ part,
                                                  int* __restrict__ bsum) {
    __shared__ int s[256];
    int i = blockIdx.x * 256 + threadIdx.x;
    int v = (i < NN) ? cnt[i] : 0;
    s[threadIdx.x] = v;
    __syncthreads();
    for (int off = 1; off < 256; off <<= 1) {
        int t = (threadIdx.x >= off) ? s[threadIdx.x - off] : 0;
        __syncthreads();
        s[threadIdx.x] += t;
        __syncthreads();
    }
    if (i < NN) part[i] = s[threadIdx.x] - v;
    if (threadIdx.x == 255) bsum[blockIdx.x] = s[255];
}

__global__ __launch_bounds__(512) void scan_partials(int* __restrict__ bsum, int nb) {
    __shared__ int s[512];
    int v = (threadIdx.x < nb) ? bsum[threadIdx.x] : 0;
    s[threadIdx.x] = v;
    __syncthreads();
    for (int off = 1; off < 512; off <<= 1) {
        int t = (threadIdx.x >= off) ? s[threadIdx.x - off] : 0;
        __syncthreads();
        s[threadIdx.x] += t;
        __syncthreads();
    }
    if (threadIdx.x < nb) bsum[threadIdx.x] = s[threadIdx.x] - v;
}

__global__ __launch_bounds__(256) void scan_add(const int* __restrict__ part,
                                                const int* __restrict__ bsum,
                                                int* __restrict__ roff,
                                                int* __restrict__ rpos) {
    int i = blockIdx.x * 256 + threadIdx.x;
    if (i < NN) {
        int v = part[i] + bsum[blockIdx.x];
        roff[i] = v; rpos[i] = v;
    }
    if (i == NN) roff[NN] = E_TOT;
}

__global__ __launch_bounds__(256) void csr_scatter(const int* __restrict__ src_a,
                                                   const int* __restrict__ dst_a,
                                                   int* __restrict__ rpos,
                                                   int* __restrict__ csr) {
    int e = blockIdx.x * 256 + threadIdx.x;
    if (e >= E_TOT) return;
    int s, d, flag;
    if (e < E_RAW) { s = src_a[e]; d = dst_a[e]; flag = (s == d); }
    else           { s = d = e - E_RAW; flag = 0; }
    int pos = atomicAdd(&rpos[d], 1);
    csr[pos] = s | (flag << 31);
}

// ========== fused GAT layer: online softmax + gather + bias + ELU ==========
// one wave per destination node; 4 waves per block
__global__ __launch_bounds__(256) void gat_fused(const int* __restrict__ roff,
                                                 const int* __restrict__ csr,
                                                 const float* __restrict__ AL,
                                                 const float* __restrict__ AR,
                                                 const float* __restrict__ Hm,
                                                 const float* __restrict__ bias,
                                                 float* __restrict__ Out) {
    const int lane = threadIdx.x & 63;
    const int n = blockIdx.x * 4 + (threadIdx.x >> 6);
    const int r0 = roff[n], r1 = roff[n + 1];

    // ---- pass A: online segment max + denom (8 lanes per head) ----
    const int hd = lane >> 3;      // head
    const int t  = lane & 7;       // edge stride slot
    const float ard = AR[n * 8 + hd];
    float m = -3e38f, den = 0.f;   // finite init: no inf-inf NaN
    for (int j = r0 + t; j < r1; j += 8) {
        int sw = csr[j];
        int s = sw & 0x7fffffff;
        float ev = AL[s * 8 + hd] + ard;
        ev = ev > 0.f ? ev : SLOPE * ev;
        float mn = fmaxf(m, ev);
        float add = (sw >= 0) ? __expf(ev - mn) : 0.f;   // mask excluded from denom
        den = fmaf(den, __expf(m - mn), add);
        m = mn;
    }
    #pragma unroll
    for (int off = 1; off < 8; off <<= 1) {
        float m2 = __shfl_xor(m, off), d2 = __shfl_xor(den, off);
        float mn = fmaxf(m, m2);
        den = den * __expf(m - mn) + d2 * __expf(m2 - mn);
        m = mn;
    }
    const float inv = 1.f / fmaxf(den, 1e-16f);

    // ---- pass B: 2 edges/iter; lane half owns an edge, float4 feats ----
    const int hf  = lane >> 5;       // which edge of the pair
    const int l32 = lane & 31;       // float4 slot in the 128-float row
    const int hd2 = l32 >> 2;        // head of feats 4*l32..4*l32+3
    const float m_b   = __shfl(m,   hd2 * 8);
    const float inv_b = __shfl(inv, hd2 * 8);
    const float ar_b  = __shfl(ard, hd2 * 8);
    float4 a = make_float4(0.f, 0.f, 0.f, 0.f);
    int j = r0;
    for (; j + 1 < r1; j += 2) {
        int sw = csr[j + hf];
        int s = sw & 0x7fffffff;
        float ev = AL[s * 8 + hd2] + ar_b;
        ev = ev > 0.f ? ev : SLOPE * ev;
        float alpha = (sw >= 0) ? __expf(ev - m_b) * inv_b : 0.f;
        const float4 hv = *(const float4*)(Hm + (size_t)s * 128 + l32 * 4);
        a.x = fmaf(hv.x, alpha, a.x);
        a.y = fmaf(hv.y, alpha, a.y);
        a.z = fmaf(hv.z, alpha, a.z);
        a.w = fmaf(hv.w, alpha, a.w);
    }
    if (j < r1 && hf == 0) {        // odd tail: half-wave handles it
        int sw = csr[j];
        int s = sw & 0x7fffffff;
        float ev = AL[s * 8 + hd2] + ar_b;
        ev = ev > 0.f ? ev : SLOPE * ev;
        float alpha = (sw >= 0) ? __expf(ev - m_b) * inv_b : 0.f;
        const float4 hv = *(const float4*)(Hm + (size_t)s * 128 + l32 * 4);
        a.x = fmaf(hv.x, alpha, a.x);
        a.y = fmaf(hv.y, alpha, a.y);
        a.z = fmaf(hv.z, alpha, a.z);
        a.w = fmaf(hv.w, alpha, a.w);
    }
    a.x += __shfl_xor(a.x, 32);
    a.y += __shfl_xor(a.y, 32);
    a.z += __shfl_xor(a.z, 32);
    a.w += __shfl_xor(a.w, 32);
    if (hf == 0) {
        const float4 bv = *(const float4*)(bias + l32 * 4);
        a.x += bv.x; a.y += bv.y; a.z += bv.z; a.w += bv.w;
        a.x = a.x > 0.f ? a.x : expm1f(a.x);
        a.y = a.y > 0.f ? a.y : expm1f(a.y);
        a.z = a.z > 0.f ? a.z : expm1f(a.z);
        a.w = a.w > 0.f ? a.w : expm1f(a.w);
        *(float4*)(Out + (size_t)n * 128 + l32 * 4) = a;
    }
}

// ================= classifier: [NN,128] @ [128,40] + bc =================
__global__ __launch_bounds__(256) void classifier(const float* __restrict__ X,
                                                  const float* __restrict__ Wc,
                                                  const float* __restrict__ bc,
                                                  float* __restrict__ Out) {
    __shared__ float ws[128 * NCLS];   // 20KB
    __shared__ float xs[32][132];      // 16.9KB
    for (int i = threadIdx.x; i < 128 * NCLS; i += 256) ws[i] = Wc[i];
    const int row0 = blockIdx.x << 5;
    for (int i = threadIdx.x; i < 32 * 128; i += 256) {
        int r = i >> 7, k = i & 127;
        xs[r][k] = X[(size_t)(row0 + r) * 128 + k];
    }
    __syncthreads();
    const int r  = threadIdx.x >> 3;
    const int c0 = (threadIdx.x & 7) * 5;
    float acc[5] = {0.f,0.f,0.f,0.f,0.f};
    for (int k = 0; k < 128; ++k) {
        float xv = xs[r][k];
        #pragma unroll
        for (int j = 0; j < 5; ++j)
            acc[j] = fmaf(xv, ws[k * NCLS + c0 + j], acc[j]);
    }
    #pragma unroll
    for (int j = 0; j < 5; ++j)
        Out[(size_t)(row0 + r) * NCLS + c0 + j] = acc[j] + bc[c0 + j];
}

extern "C" void kernel_launch(void* const* d_in, const int* in_sizes, int n_in,
                              void* d_out, int out_size, void* d_ws, size_t ws_size,
                              hipStream_t stream) {
    const float* x    = (const float*)d_in[0];
    const int*   ei   = (const int*)  d_in[1];
    // d_in[2] edge_weight: unused (matches reference)
    const float* W1   = (const float*)d_in[3];
    const float* al1  = (const float*)d_in[4];
    const float* ar1  = (const float*)d_in[5];
    const float* b1   = (const float*)d_in[6];
    const float* W2   = (const float*)d_in[7];
    const float* al2  = (const float*)d_in[8];
    const float* ar2  = (const float*)d_in[9];
    const float* b2   = (const float*)d_in[10];
    const float* Wc   = (const float*)d_in[11];
    const float* bc   = (const float*)d_in[12];
    float* out = (float*)d_out;

    const int* src = ei;
    const int* dst = ei + E_RAW;

    char* ws = (char*)d_ws;
    float* h    = (float*)(ws);                        // 51.2 MB
    float* acc  = (float*)(ws + 51200000UL);           // 51.2 MB
    float* AL   = (float*)(ws + 102400000UL);          // 3.2 MB
    float* AR   = (float*)(ws + 105600000UL);          // 3.2 MB
    int*   csr  = (int*)  (ws + 108800000UL);          // 6.8 MB
    int*   cnt  = (int*)  (ws + 115600000UL);          // 0.4 MB
    int*   roff = (int*)  (ws + 116000000UL);          // 0.4 MB (+4)
    int*   rpos = (int*)  (ws + 116400004UL);          // 0.4 MB
    int*   part = (int*)  (ws + 116800004UL);          // 0.4 MB
    int*   bsum = (int*)  (ws + 117200004UL);          // 2 KB

    const int NB_N    = (NN + 255) / 256;              // 391
    const int gRaw    = (E_RAW + 255) / 256;           // 6250
    const int gTot    = (E_TOT + 255) / 256;           // 6641
    const int gRows32 = NN / 32;                       // 3125
    const int gGat    = NN / 4;                        // 25000

    // ---- CSR build (shared by both layers) ----
    csr_init_cnt<<<NB_N, 256, 0, stream>>>(cnt);
    csr_hist<<<gRaw, 256, 0, stream>>>(dst, cnt);
    scan_block<<<NB_N, 256, 0, stream>>>(cnt, part, bsum);
    scan_partials<<<1, 512, 0, stream>>>(bsum, NB_N);
    scan_add<<<NB_N, 256, 0, stream>>>(part, bsum, roff, rpos);
    csr_scatter<<<gTot, 256, 0, stream>>>(src, dst, rpos, csr);

    // ---- layer 1 ----
    gemm128_alar<<<gRows32, 256, 0, stream>>>(x, W1, al1, ar1, h, AL, AR);
    gat_fused<<<gGat, 256, 0, stream>>>(roff, csr, AL, AR, h, b1, acc);

    // ---- layer 2 ----
    gemm128_alar<<<gRows32, 256, 0, stream>>>(acc, W2, al2, ar2, h, AL, AR);
    gat_fused<<<gGat, 256, 0, stream>>>(roff, csr, AL, AR, h, b2, acc);

    // ---- classifier ----
    classifier<<<gRows32, 256, 0, stream>>>(acc, Wc, bc, out);
}

// Round 7
// 793.581 us; speedup vs baseline: 10.6568x; 1.1396x over previous
//
#include <hip/hip_runtime.h>
#include <hip/hip_bf16.h>
#include <math.h>

#define NN 100000
#define E_RAW 1600000
#define E_TOT 1700000
#define HEADS 8
#define CH 16
#define FDIM 128
#define NCLS 40
#define SLOPE 0.2f

__device__ __forceinline__ float elu1(float v) { return v > 0.f ? v : expm1f(v); }

// ========== GEMM [NN,128]@[128,128] + fused AL/AR epilogue ==========
// 32 rows/block; thread = (rgrp 0..3) x (cpair 0..63): 8 rows x 2 cols each
__global__ __launch_bounds__(256) void gemm128_alar(const float* __restrict__ X,
                                                    const float* __restrict__ Wm,
                                                    const float* __restrict__ attl,
                                                    const float* __restrict__ attr,
                                                    float* __restrict__ Out,
                                                    float* __restrict__ AL,
                                                    float* __restrict__ AR) {
    __shared__ float xs[32][132];
    const int cpair = threadIdx.x & 63;     // cols 2*cpair, 2*cpair+1
    const int rgrp  = threadIdx.x >> 6;     // rows rgrp*8 .. +7
    const int row0 = blockIdx.x << 5;       // 100000 % 32 == 0
    for (int i = threadIdx.x; i < 32 * 128; i += 256) {
        int r = i >> 7, k = i & 127;
        xs[r][k] = X[(size_t)(row0 + r) * 128 + k];
    }
    __syncthreads();
    float acc[8][2];
    #pragma unroll
    for (int r = 0; r < 8; ++r) { acc[r][0] = 0.f; acc[r][1] = 0.f; }
    const float* wp = Wm + 2 * cpair;
    for (int k = 0; k < 128; k += 4) {
        float w00 = wp[(k+0)*128], w01 = wp[(k+0)*128 + 1];
        float w10 = wp[(k+1)*128], w11 = wp[(k+1)*128 + 1];
        float w20 = wp[(k+2)*128], w21 = wp[(k+2)*128 + 1];
        float w30 = wp[(k+3)*128], w31 = wp[(k+3)*128 + 1];
        #pragma unroll
        for (int r = 0; r < 8; ++r) {
            const float4 xv = *(const float4*)&xs[rgrp*8 + r][k];
            acc[r][0] = fmaf(xv.w, w30, fmaf(xv.z, w20, fmaf(xv.y, w10, fmaf(xv.x, w00, acc[r][0]))));
            acc[r][1] = fmaf(xv.w, w31, fmaf(xv.z, w21, fmaf(xv.y, w11, fmaf(xv.x, w01, acc[r][1]))));
        }
    }
    #pragma unroll
    for (int r = 0; r < 8; ++r)
        *(float2*)&Out[(size_t)(row0 + rgrp*8 + r) * 128 + 2*cpair] =
            make_float2(acc[r][0], acc[r][1]);

    // ---- fused AL/AR: reduce 16 cols (8 lanes x 2) per head ----
    const float lw0 = attl[2*cpair], lw1 = attl[2*cpair+1];
    const float rw0 = attr[2*cpair], rw1 = attr[2*cpair+1];
    const int hd = cpair >> 3;
    #pragma unroll
    for (int r = 0; r < 8; ++r) {
        float pl = acc[r][0]*lw0 + acc[r][1]*lw1;
        float pr = acc[r][0]*rw0 + acc[r][1]*rw1;
        #pragma unroll
        for (int off = 1; off < 8; off <<= 1) {
            pl += __shfl_xor(pl, off);
            pr += __shfl_xor(pr, off);
        }
        if ((cpair & 7) == 0) {
            int nd = row0 + rgrp*8 + r;
            AL[nd*8 + hd] = pl;
            AR[nd*8 + hd] = pr;
        }
    }
}

// ================= CSR build =================
__global__ __launch_bounds__(256) void csr_init_cnt(int* __restrict__ cnt) {
    int i = blockIdx.x * 256 + threadIdx.x;
    if (i < NN) cnt[i] = 1;   // self-loop
}

__global__ __launch_bounds__(256) void csr_hist(const int* __restrict__ dst_a,
                                                int* __restrict__ cnt) {
    int e = blockIdx.x * 256 + threadIdx.x;
    if (e < E_RAW) atomicAdd(&cnt[dst_a[e]], 1);
}

__global__ __launch_bounds__(256) void scan_block(const int* __restrict__ cnt,
                                                  int* __restrict__ part,
                                                  int* __restrict__ bsum) {
    __shared__ int s[256];
    int i = blockIdx.x * 256 + threadIdx.x;
    int v = (i < NN) ? cnt[i] : 0;
    s[threadIdx.x] = v;
    __syncthreads();
    for (int off = 1; off < 256; off <<= 1) {
        int t = (threadIdx.x >= off) ? s[threadIdx.x - off] : 0;
        __syncthreads();
        s[threadIdx.x] += t;
        __syncthreads();
    }
    if (i < NN) part[i] = s[threadIdx.x] - v;
    if (threadIdx.x == 255) bsum[blockIdx.x] = s[255];
}

__global__ __launch_bounds__(512) void scan_partials(int* __restrict__ bsum, int nb) {
    __shared__ int s[512];
    int v = (threadIdx.x < nb) ? bsum[threadIdx.x] : 0;
    s[threadIdx.x] = v;
    __syncthreads();
    for (int off = 1; off < 512; off <<= 1) {
        int t = (threadIdx.x >= off) ? s[threadIdx.x - off] : 0;
        __syncthreads();
        s[threadIdx.x] += t;
        __syncthreads();
    }
    if (threadIdx.x < nb) bsum[threadIdx.x] = s[threadIdx.x] - v;
}

__global__ __launch_bounds__(256) void scan_add(const int* __restrict__ part,
                                                const int* __restrict__ bsum,
                                                int* __restrict__ roff,
                                                int* __restrict__ rpos) {
    int i = blockIdx.x * 256 + threadIdx.x;
    if (i < NN) {
        int v = part[i] + bsum[blockIdx.x];
        roff[i] = v; rpos[i] = v;
    }
    if (i == NN) roff[NN] = E_TOT;
}

__global__ __launch_bounds__(256) void csr_scatter(const int* __restrict__ src_a,
                                                   const int* __restrict__ dst_a,
                                                   int* __restrict__ rpos,
                                                   int* __restrict__ csr) {
    int e = blockIdx.x * 256 + threadIdx.x;
    if (e >= E_TOT) return;
    int s, d, flag;
    if (e < E_RAW) { s = src_a[e]; d = dst_a[e]; flag = (s == d); }
    else           { s = d = e - E_RAW; flag = 0; }
    int pos = atomicAdd(&rpos[d], 1);
    csr[pos] = s | (flag << 31);
}

// ========== fused GAT layer: online softmax + gather + bias + ELU ==========
// one wave per destination node; 4 waves per block.
// pass B: 8 edges in flight; lane = ef*8 + fl, fl = head = feat block of 16
__global__ __launch_bounds__(256) void gat_fused(const int* __restrict__ roff,
                                                 const int* __restrict__ csr,
                                                 const float* __restrict__ AL,
                                                 const float* __restrict__ AR,
                                                 const float* __restrict__ Hm,
                                                 const float* __restrict__ bias,
                                                 float* __restrict__ Out) {
    const int lane = threadIdx.x & 63;
    const int n = blockIdx.x * 4 + (threadIdx.x >> 6);
    const int r0 = roff[n], r1 = roff[n + 1];

    // ---- pass A: online segment max + denom (8 lanes per head) ----
    const int hd = lane >> 3;
    const int t  = lane & 7;
    const float ard = AR[n * 8 + hd];
    float m = -3e38f, den = 0.f;   // finite init: no inf-inf NaN
    for (int j = r0 + t; j < r1; j += 8) {
        int sw = csr[j];
        int s = sw & 0x7fffffff;
        float ev = AL[s * 8 + hd] + ard;
        ev = ev > 0.f ? ev : SLOPE * ev;
        float mn = fmaxf(m, ev);
        float add = (sw >= 0) ? __expf(ev - mn) : 0.f;   // masked dups excluded
        den = fmaf(den, __expf(m - mn), add);
        m = mn;
    }
    #pragma unroll
    for (int off = 1; off < 8; off <<= 1) {
        float m2 = __shfl_xor(m, off), d2 = __shfl_xor(den, off);
        float mn = fmaxf(m, m2);
        den = den * __expf(m - mn) + d2 * __expf(m2 - mn);
        m = mn;
    }
    const float inv = 1.f / fmaxf(den, 1e-16f);

    // ---- pass B: 8 edges/iter, 8 lanes (one head's 16 feats) per edge ----
    const int ef = lane >> 3;      // edge slot 0..7
    const int fl = lane & 7;       // head & feat-block: feats fl*16 .. +15
    const float m_b   = __shfl(m,   fl * 8);
    const float inv_b = __shfl(inv, fl * 8);
    const float ar_b  = __shfl(ard, fl * 8);
    float4 a0 = make_float4(0.f,0.f,0.f,0.f), a1 = a0, a2 = a0, a3 = a0;
    for (int j = r0; j < r1; j += 8) {
        int jj = j + ef;
        if (jj < r1) {
            int sw = csr[jj];
            int s = sw & 0x7fffffff;
            float ev = AL[s * 8 + fl] + ar_b;
            ev = ev > 0.f ? ev : SLOPE * ev;
            float alpha = (sw >= 0) ? __expf(ev - m_b) * inv_b : 0.f;
            const float4* hp = (const float4*)(Hm + (size_t)s * 128 + fl * 16);
            float4 h0 = hp[0], h1 = hp[1], h2 = hp[2], h3 = hp[3];
            a0.x = fmaf(h0.x, alpha, a0.x); a0.y = fmaf(h0.y, alpha, a0.y);
            a0.z = fmaf(h0.z, alpha, a0.z); a0.w = fmaf(h0.w, alpha, a0.w);
            a1.x = fmaf(h1.x, alpha, a1.x); a1.y = fmaf(h1.y, alpha, a1.y);
            a1.z = fmaf(h1.z, alpha, a1.z); a1.w = fmaf(h1.w, alpha, a1.w);
            a2.x = fmaf(h2.x, alpha, a2.x); a2.y = fmaf(h2.y, alpha, a2.y);
            a2.z = fmaf(h2.z, alpha, a2.z); a2.w = fmaf(h2.w, alpha, a2.w);
            a3.x = fmaf(h3.x, alpha, a3.x); a3.y = fmaf(h3.y, alpha, a3.y);
            a3.z = fmaf(h3.z, alpha, a3.z); a3.w = fmaf(h3.w, alpha, a3.w);
        }
    }
    #pragma unroll
    for (int off = 8; off < 64; off <<= 1) {
        a0.x += __shfl_xor(a0.x, off); a0.y += __shfl_xor(a0.y, off);
        a0.z += __shfl_xor(a0.z, off); a0.w += __shfl_xor(a0.w, off);
        a1.x += __shfl_xor(a1.x, off); a1.y += __shfl_xor(a1.y, off);
        a1.z += __shfl_xor(a1.z, off); a1.w += __shfl_xor(a1.w, off);
        a2.x += __shfl_xor(a2.x, off); a2.y += __shfl_xor(a2.y, off);
        a2.z += __shfl_xor(a2.z, off); a2.w += __shfl_xor(a2.w, off);
        a3.x += __shfl_xor(a3.x, off); a3.y += __shfl_xor(a3.y, off);
        a3.z += __shfl_xor(a3.z, off); a3.w += __shfl_xor(a3.w, off);
    }
    if (lane < 8) {                    // ef==0, fl==lane
        const float4* bp = (const float4*)(bias + lane * 16);
        float4 b0 = bp[0], b1 = bp[1], b2 = bp[2], b3 = bp[3];
        a0.x = elu1(a0.x + b0.x); a0.y = elu1(a0.y + b0.y);
        a0.z = elu1(a0.z + b0.z); a0.w = elu1(a0.w + b0.w);
        a1.x = elu1(a1.x + b1.x); a1.y = elu1(a1.y + b1.y);
        a1.z = elu1(a1.z + b1.z); a1.w = elu1(a1.w + b1.w);
        a2.x = elu1(a2.x + b2.x); a2.y = elu1(a2.y + b2.y);
        a2.z = elu1(a2.z + b2.z); a2.w = elu1(a2.w + b2.w);
        a3.x = elu1(a3.x + b3.x); a3.y = elu1(a3.y + b3.y);
        a3.z = elu1(a3.z + b3.z); a3.w = elu1(a3.w + b3.w);
        float4* op = (float4*)(Out + (size_t)n * 128 + lane * 16);
        op[0] = a0; op[1] = a1; op[2] = a2; op[3] = a3;
    }
}

// ================= classifier: [NN,128] @ [128,40] + bc =================
__global__ __launch_bounds__(256) void classifier(const float* __restrict__ X,
                                                  const float* __restrict__ Wc,
                                                  const float* __restrict__ bc,
                                                  float* __restrict__ Out) {
    __shared__ float ws[128 * NCLS];   // 20KB
    __shared__ float xs[32][132];      // 16.9KB
    for (int i = threadIdx.x; i < 128 * NCLS; i += 256) ws[i] = Wc[i];
    const int row0 = blockIdx.x << 5;
    for (int i = threadIdx.x; i < 32 * 128; i += 256) {
        int r = i >> 7, k = i & 127;
        xs[r][k] = X[(size_t)(row0 + r) * 128 + k];
    }
    __syncthreads();
    const int r  = threadIdx.x >> 3;
    const int c0 = (threadIdx.x & 7) * 5;
    float acc[5] = {0.f,0.f,0.f,0.f,0.f};
    for (int k = 0; k < 128; ++k) {
        float xv = xs[r][k];
        #pragma unroll
        for (int j = 0; j < 5; ++j)
            acc[j] = fmaf(xv, ws[k * NCLS + c0 + j], acc[j]);
    }
    #pragma unroll
    for (int j = 0; j < 5; ++j)
        Out[(size_t)(row0 + r) * NCLS + c0 + j] = acc[j] + bc[c0 + j];
}

extern "C" void kernel_launch(void* const* d_in, const int* in_sizes, int n_in,
                              void* d_out, int out_size, void* d_ws, size_t ws_size,
                              hipStream_t stream) {
    const float* x    = (const float*)d_in[0];
    const int*   ei   = (const int*)  d_in[1];
    // d_in[2] edge_weight: unused (matches reference)
    const float* W1   = (const float*)d_in[3];
    const float* al1  = (const float*)d_in[4];
    const float* ar1  = (const float*)d_in[5];
    const float* b1   = (const float*)d_in[6];
    const float* W2   = (const float*)d_in[7];
    const float* al2  = (const float*)d_in[8];
    const float* ar2  = (const float*)d_in[9];
    const float* b2   = (const float*)d_in[10];
    const float* Wc   = (const float*)d_in[11];
    const float* bc   = (const float*)d_in[12];
    float* out = (float*)d_out;

    const int* src = ei;
    const int* dst = ei + E_RAW;

    char* ws = (char*)d_ws;
    float* h    = (float*)(ws);                        // 51.2 MB
    float* acc  = (float*)(ws + 51200000UL);           // 51.2 MB
    float* AL   = (float*)(ws + 102400000UL);          // 3.2 MB
    float* AR   = (float*)(ws + 105600000UL);          // 3.2 MB
    int*   csr  = (int*)  (ws + 108800000UL);          // 6.8 MB
    int*   cnt  = (int*)  (ws + 115600000UL);          // 0.4 MB
    int*   roff = (int*)  (ws + 116000000UL);          // 0.4 MB (+4)
    int*   rpos = (int*)  (ws + 116400004UL);          // 0.4 MB
    int*   part = (int*)  (ws + 116800004UL);          // 0.4 MB
    int*   bsum = (int*)  (ws + 117200004UL);          // 2 KB

    const int NB_N    = (NN + 255) / 256;              // 391
    const int gRaw    = (E_RAW + 255) / 256;           // 6250
    const int gTot    = (E_TOT + 255) / 256;           // 6641
    const int gRows32 = NN / 32;                       // 3125
    const int gGat    = NN / 4;                        // 25000

    // ---- CSR build (shared by both layers) ----
    csr_init_cnt<<<NB_N, 256, 0, stream>>>(cnt);
    csr_hist<<<gRaw, 256, 0, stream>>>(dst, cnt);
    scan_block<<<NB_N, 256, 0, stream>>>(cnt, part, bsum);
    scan_partials<<<1, 512, 0, stream>>>(bsum, NB_N);
    scan_add<<<NB_N, 256, 0, stream>>>(part, bsum, roff, rpos);
    csr_scatter<<<gTot, 256, 0, stream>>>(src, dst, rpos, csr);

    // ---- layer 1 ----
    gemm128_alar<<<gRows32, 256, 0, stream>>>(x, W1, al1, ar1, h, AL, AR);
    gat_fused<<<gGat, 256, 0, stream>>>(roff, csr, AL, AR, h, b1, acc);

    // ---- layer 2 ----
    gemm128_alar<<<gRows32, 256, 0, stream>>>(acc, W2, al2, ar2, h, AL, AR);
    gat_fused<<<gGat, 256, 0, stream>>>(roff, csr, AL, AR, h, b2, acc);

    // ---- classifier ----
    classifier<<<gRows32, 256, 0, stream>>>(acc, Wc, bc, out);
}

// Round 8
// 713.888 us; speedup vs baseline: 11.8464x; 1.1116x over previous
//
#include <hip/hip_runtime.h>
#include <hip/hip_bf16.h>
#include <math.h>

#define NN 100000
#define E_RAW 1600000
#define E_TOT 1700000
#define HEADS 8
#define CH 16
#define FDIM 128
#define NCLS 40
#define SLOPE 0.2f

__device__ __forceinline__ float elu1(float v) { return v > 0.f ? v : expm1f(v); }

__device__ __forceinline__ unsigned short f2bf(float f) {   // RNE bf16
    unsigned int u = __float_as_uint(f);
    u += 0x7fffu + ((u >> 16) & 1u);
    return (unsigned short)(u >> 16);
}

// ========== GEMM [NN,128]@[128,128] -> bf16 h + fused AL/AR epilogue ==========
// 32 rows/block; thread = (rgrp 0..3) x (cpair 0..63): 8 rows x 2 cols each
__global__ __launch_bounds__(256) void gemm128_alar(const float* __restrict__ X,
                                                    const float* __restrict__ Wm,
                                                    const float* __restrict__ attl,
                                                    const float* __restrict__ attr,
                                                    unsigned short* __restrict__ Hb,
                                                    float* __restrict__ AL,
                                                    float* __restrict__ AR) {
    __shared__ float xs[32][132];
    const int cpair = threadIdx.x & 63;     // cols 2*cpair, 2*cpair+1
    const int rgrp  = threadIdx.x >> 6;     // rows rgrp*8 .. +7
    const int row0 = blockIdx.x << 5;       // 100000 % 32 == 0
    for (int i = threadIdx.x; i < 32 * 128; i += 256) {
        int r = i >> 7, k = i & 127;
        xs[r][k] = X[(size_t)(row0 + r) * 128 + k];
    }
    __syncthreads();
    float acc[8][2];
    #pragma unroll
    for (int r = 0; r < 8; ++r) { acc[r][0] = 0.f; acc[r][1] = 0.f; }
    const float* wp = Wm + 2 * cpair;
    for (int k = 0; k < 128; k += 4) {
        float w00 = wp[(k+0)*128], w01 = wp[(k+0)*128 + 1];
        float w10 = wp[(k+1)*128], w11 = wp[(k+1)*128 + 1];
        float w20 = wp[(k+2)*128], w21 = wp[(k+2)*128 + 1];
        float w30 = wp[(k+3)*128], w31 = wp[(k+3)*128 + 1];
        #pragma unroll
        for (int r = 0; r < 8; ++r) {
            const float4 xv = *(const float4*)&xs[rgrp*8 + r][k];
            acc[r][0] = fmaf(xv.w, w30, fmaf(xv.z, w20, fmaf(xv.y, w10, fmaf(xv.x, w00, acc[r][0]))));
            acc[r][1] = fmaf(xv.w, w31, fmaf(xv.z, w21, fmaf(xv.y, w11, fmaf(xv.x, w01, acc[r][1]))));
        }
    }
    #pragma unroll
    for (int r = 0; r < 8; ++r) {
        ushort2 p; p.x = f2bf(acc[r][0]); p.y = f2bf(acc[r][1]);
        *(ushort2*)&Hb[(size_t)(row0 + rgrp*8 + r) * 128 + 2*cpair] = p;
    }

    // ---- fused AL/AR: reduce 16 cols (8 lanes x 2) per head ----
    const float lw0 = attl[2*cpair], lw1 = attl[2*cpair+1];
    const float rw0 = attr[2*cpair], rw1 = attr[2*cpair+1];
    const int hd = cpair >> 3;
    #pragma unroll
    for (int r = 0; r < 8; ++r) {
        float pl = acc[r][0]*lw0 + acc[r][1]*lw1;
        float pr = acc[r][0]*rw0 + acc[r][1]*rw1;
        #pragma unroll
        for (int off = 1; off < 8; off <<= 1) {
            pl += __shfl_xor(pl, off);
            pr += __shfl_xor(pr, off);
        }
        if ((cpair & 7) == 0) {
            int nd = row0 + rgrp*8 + r;
            AL[nd*8 + hd] = pl;
            AR[nd*8 + hd] = pr;
        }
    }
}

// ================= CSR build =================
__global__ __launch_bounds__(256) void csr_init_cnt(int* __restrict__ cnt) {
    int i = blockIdx.x * 256 + threadIdx.x;
    if (i < NN) cnt[i] = 1;   // self-loop
}

__global__ __launch_bounds__(256) void csr_hist(const int* __restrict__ dst_a,
                                                int* __restrict__ cnt) {
    int e = blockIdx.x * 256 + threadIdx.x;
    if (e < E_RAW) atomicAdd(&cnt[dst_a[e]], 1);
}

__global__ __launch_bounds__(256) void scan_block(const int* __restrict__ cnt,
                                                  int* __restrict__ part,
                                                  int* __restrict__ bsum) {
    __shared__ int s[256];
    int i = blockIdx.x * 256 + threadIdx.x;
    int v = (i < NN) ? cnt[i] : 0;
    s[threadIdx.x] = v;
    __syncthreads();
    for (int off = 1; off < 256; off <<= 1) {
        int t = (threadIdx.x >= off) ? s[threadIdx.x - off] : 0;
        __syncthreads();
        s[threadIdx.x] += t;
        __syncthreads();
    }
    if (i < NN) part[i] = s[threadIdx.x] - v;
    if (threadIdx.x == 255) bsum[blockIdx.x] = s[255];
}

__global__ __launch_bounds__(512) void scan_partials(int* __restrict__ bsum, int nb) {
    __shared__ int s[512];
    int v = (threadIdx.x < nb) ? bsum[threadIdx.x] : 0;
    s[threadIdx.x] = v;
    __syncthreads();
    for (int off = 1; off < 512; off <<= 1) {
        int t = (threadIdx.x >= off) ? s[threadIdx.x - off] : 0;
        __syncthreads();
        s[threadIdx.x] += t;
        __syncthreads();
    }
    if (threadIdx.x < nb) bsum[threadIdx.x] = s[threadIdx.x] - v;
}

__global__ __launch_bounds__(256) void scan_add(const int* __restrict__ part,
                                                const int* __restrict__ bsum,
                                                int* __restrict__ roff,
                                                int* __restrict__ rpos) {
    int i = blockIdx.x * 256 + threadIdx.x;
    if (i < NN) {
        int v = part[i] + bsum[blockIdx.x];
        roff[i] = v; rpos[i] = v;
    }
    if (i == NN) roff[NN] = E_TOT;
}

__global__ __launch_bounds__(256) void csr_scatter(const int* __restrict__ src_a,
                                                   const int* __restrict__ dst_a,
                                                   int* __restrict__ rpos,
                                                   int* __restrict__ csr) {
    int e = blockIdx.x * 256 + threadIdx.x;
    if (e >= E_TOT) return;
    int s, d, flag;
    if (e < E_RAW) { s = src_a[e]; d = dst_a[e]; flag = (s == d); }
    else           { s = d = e - E_RAW; flag = 0; }
    int pos = atomicAdd(&rpos[d], 1);
    csr[pos] = s | (flag << 31);
}

// ========== fused GAT layer: online softmax + bf16 gather + bias + ELU ==========
// one wave per destination node; 4 waves per block.
// pass B: 8 edges in flight; lane = ef*8 + fl, fl = head = feat block of 16
__global__ __launch_bounds__(256) void gat_fused(const int* __restrict__ roff,
                                                 const int* __restrict__ csr,
                                                 const float* __restrict__ AL,
                                                 const float* __restrict__ AR,
                                                 const unsigned short* __restrict__ Hb,
                                                 const float* __restrict__ bias,
                                                 float* __restrict__ Out) {
    const int lane = threadIdx.x & 63;
    const int n = blockIdx.x * 4 + (threadIdx.x >> 6);
    const int r0 = roff[n], r1 = roff[n + 1];

    // ---- pass A: online segment max + denom (8 lanes per head) ----
    const int hd = lane >> 3;
    const int t  = lane & 7;
    const float ard = AR[n * 8 + hd];
    float m = -3e38f, den = 0.f;   // finite init: no inf-inf NaN
    for (int j = r0 + t; j < r1; j += 8) {
        int sw = csr[j];
        int s = sw & 0x7fffffff;
        float ev = AL[s * 8 + hd] + ard;
        ev = fmaxf(ev, SLOPE * ev);                       // LeakyReLU
        float mn = fmaxf(m, ev);
        float add = (sw >= 0) ? __expf(ev - mn) : 0.f;    // masked dups excluded
        den = fmaf(den, __expf(m - mn), add);
        m = mn;
    }
    #pragma unroll
    for (int off = 1; off < 8; off <<= 1) {
        float m2 = __shfl_xor(m, off), d2 = __shfl_xor(den, off);
        float mn = fmaxf(m, m2);
        den = den * __expf(m - mn) + d2 * __expf(m2 - mn);
        m = mn;
    }
    // fold 1/den into exponent: alpha = exp(ev - S), S = m + log(den)
    const float S = m + __logf(fmaxf(den, 1e-16f));

    // ---- pass B: 8 edges/iter, 8 lanes (one head's 16 feats) per edge ----
    const int ef = lane >> 3;      // edge slot 0..7
    const int fl = lane & 7;       // head & feat-block: feats fl*16 .. +15
    const float S_b  = __shfl(S,   fl * 8);
    const float ar_b = __shfl(ard, fl * 8);
    float4 a0 = make_float4(0.f,0.f,0.f,0.f), a1 = a0, a2 = a0, a3 = a0;
    for (int j = r0; j < r1; j += 8) {
        int jj = j + ef;
        if (jj < r1) {
            int sw = csr[jj];
            int s = sw & 0x7fffffff;
            float ev = AL[s * 8 + fl] + ar_b;
            ev = fmaxf(ev, SLOPE * ev);
            float alpha = (sw >= 0) ? __expf(ev - S_b) : 0.f;
            const unsigned short* hp = Hb + (size_t)s * 128 + fl * 16;
            const uint4 q0 = *(const uint4*)hp;           // feats 0..7
            const uint4 q1 = *(const uint4*)(hp + 8);     // feats 8..15
            a0.x = fmaf(__uint_as_float(q0.x << 16),          alpha, a0.x);
            a0.y = fmaf(__uint_as_float(q0.x & 0xffff0000u),  alpha, a0.y);
            a0.z = fmaf(__uint_as_float(q0.y << 16),          alpha, a0.z);
            a0.w = fmaf(__uint_as_float(q0.y & 0xffff0000u),  alpha, a0.w);
            a1.x = fmaf(__uint_as_float(q0.z << 16),          alpha, a1.x);
            a1.y = fmaf(__uint_as_float(q0.z & 0xffff0000u),  alpha, a1.y);
            a1.z = fmaf(__uint_as_float(q0.w << 16),          alpha, a1.z);
            a1.w = fmaf(__uint_as_float(q0.w & 0xffff0000u),  alpha, a1.w);
            a2.x = fmaf(__uint_as_float(q1.x << 16),          alpha, a2.x);
            a2.y = fmaf(__uint_as_float(q1.x & 0xffff0000u),  alpha, a2.y);
            a2.z = fmaf(__uint_as_float(q1.y << 16),          alpha, a2.z);
            a2.w = fmaf(__uint_as_float(q1.y & 0xffff0000u),  alpha, a2.w);
            a3.x = fmaf(__uint_as_float(q1.z << 16),          alpha, a3.x);
            a3.y = fmaf(__uint_as_float(q1.z & 0xffff0000u),  alpha, a3.y);
            a3.z = fmaf(__uint_as_float(q1.w << 16),          alpha, a3.z);
            a3.w = fmaf(__uint_as_float(q1.w & 0xffff0000u),  alpha, a3.w);
        }
    }
    #pragma unroll
    for (int off = 8; off < 64; off <<= 1) {
        a0.x += __shfl_xor(a0.x, off); a0.y += __shfl_xor(a0.y, off);
        a0.z += __shfl_xor(a0.z, off); a0.w += __shfl_xor(a0.w, off);
        a1.x += __shfl_xor(a1.x, off); a1.y += __shfl_xor(a1.y, off);
        a1.z += __shfl_xor(a1.z, off); a1.w += __shfl_xor(a1.w, off);
        a2.x += __shfl_xor(a2.x, off); a2.y += __shfl_xor(a2.y, off);
        a2.z += __shfl_xor(a2.z, off); a2.w += __shfl_xor(a2.w, off);
        a3.x += __shfl_xor(a3.x, off); a3.y += __shfl_xor(a3.y, off);
        a3.z += __shfl_xor(a3.z, off); a3.w += __shfl_xor(a3.w, off);
    }
    if (lane < 8) {                    // ef==0, fl==lane
        const float4* bp = (const float4*)(bias + lane * 16);
        float4 b0 = bp[0], b1 = bp[1], b2 = bp[2], b3 = bp[3];
        a0.x = elu1(a0.x + b0.x); a0.y = elu1(a0.y + b0.y);
        a0.z = elu1(a0.z + b0.z); a0.w = elu1(a0.w + b0.w);
        a1.x = elu1(a1.x + b1.x); a1.y = elu1(a1.y + b1.y);
        a1.z = elu1(a1.z + b1.z); a1.w = elu1(a1.w + b1.w);
        a2.x = elu1(a2.x + b2.x); a2.y = elu1(a2.y + b2.y);
        a2.z = elu1(a2.z + b2.z); a2.w = elu1(a2.w + b2.w);
        a3.x = elu1(a3.x + b3.x); a3.y = elu1(a3.y + b3.y);
        a3.z = elu1(a3.z + b3.z); a3.w = elu1(a3.w + b3.w);
        float4* op = (float4*)(Out + (size_t)n * 128 + lane * 16);
        op[0] = a0; op[1] = a1; op[2] = a2; op[3] = a3;
    }
}

// ================= classifier: [NN,128] @ [128,40] + bc =================
__global__ __launch_bounds__(256) void classifier(const float* __restrict__ X,
                                                  const float* __restrict__ Wc,
                                                  const float* __restrict__ bc,
                                                  float* __restrict__ Out) {
    __shared__ float ws[128 * NCLS];   // 20KB
    __shared__ float xs[32][132];      // 16.9KB
    for (int i = threadIdx.x; i < 128 * NCLS; i += 256) ws[i] = Wc[i];
    const int row0 = blockIdx.x << 5;
    for (int i = threadIdx.x; i < 32 * 128; i += 256) {
        int r = i >> 7, k = i & 127;
        xs[r][k] = X[(size_t)(row0 + r) * 128 + k];
    }
    __syncthreads();
    const int r  = threadIdx.x >> 3;
    const int c0 = (threadIdx.x & 7) * 5;
    float acc[5] = {0.f,0.f,0.f,0.f,0.f};
    for (int k = 0; k < 128; ++k) {
        float xv = xs[r][k];
        #pragma unroll
        for (int j = 0; j < 5; ++j)
            acc[j] = fmaf(xv, ws[k * NCLS + c0 + j], acc[j]);
    }
    #pragma unroll
    for (int j = 0; j < 5; ++j)
        Out[(size_t)(row0 + r) * NCLS + c0 + j] = acc[j] + bc[c0 + j];
}

extern "C" void kernel_launch(void* const* d_in, const int* in_sizes, int n_in,
                              void* d_out, int out_size, void* d_ws, size_t ws_size,
                              hipStream_t stream) {
    const float* x    = (const float*)d_in[0];
    const int*   ei   = (const int*)  d_in[1];
    // d_in[2] edge_weight: unused (matches reference)
    const float* W1   = (const float*)d_in[3];
    const float* al1  = (const float*)d_in[4];
    const float* ar1  = (const float*)d_in[5];
    const float* b1   = (const float*)d_in[6];
    const float* W2   = (const float*)d_in[7];
    const float* al2  = (const float*)d_in[8];
    const float* ar2  = (const float*)d_in[9];
    const float* b2   = (const float*)d_in[10];
    const float* Wc   = (const float*)d_in[11];
    const float* bc   = (const float*)d_in[12];
    float* out = (float*)d_out;

    const int* src = ei;
    const int* dst = ei + E_RAW;

    char* ws = (char*)d_ws;
    unsigned short* hb = (unsigned short*)(ws);        // 25.6 MB (bf16 h)
    float* acc  = (float*)(ws + 51200000UL);           // 51.2 MB
    float* AL   = (float*)(ws + 102400000UL);          // 3.2 MB
    float* AR   = (float*)(ws + 105600000UL);          // 3.2 MB
    int*   csr  = (int*)  (ws + 108800000UL);          // 6.8 MB
    int*   cnt  = (int*)  (ws + 115600000UL);          // 0.4 MB
    int*   roff = (int*)  (ws + 116000000UL);          // 0.4 MB (+4)
    int*   rpos = (int*)  (ws + 116400004UL);          // 0.4 MB
    int*   part = (int*)  (ws + 116800004UL);          // 0.4 MB
    int*   bsum = (int*)  (ws + 117200004UL);          // 2 KB

    const int NB_N    = (NN + 255) / 256;              // 391
    const int gRaw    = (E_RAW + 255) / 256;           // 6250
    const int gTot    = (E_TOT + 255) / 256;           // 6641
    const int gRows32 = NN / 32;                       // 3125
    const int gGat    = NN / 4;                        // 25000

    // ---- CSR build (shared by both layers) ----
    csr_init_cnt<<<NB_N, 256, 0, stream>>>(cnt);
    csr_hist<<<gRaw, 256, 0, stream>>>(dst, cnt);
    scan_block<<<NB_N, 256, 0, stream>>>(cnt, part, bsum);
    scan_partials<<<1, 512, 0, stream>>>(bsum, NB_N);
    scan_add<<<NB_N, 256, 0, stream>>>(part, bsum, roff, rpos);
    csr_scatter<<<gTot, 256, 0, stream>>>(src, dst, rpos, csr);

    // ---- layer 1 ----
    gemm128_alar<<<gRows32, 256, 0, stream>>>(x, W1, al1, ar1, hb, AL, AR);
    gat_fused<<<gGat, 256, 0, stream>>>(roff, csr, AL, AR, hb, b1, acc);

    // ---- layer 2 ----
    gemm128_alar<<<gRows32, 256, 0, stream>>>(acc, W2, al2, ar2, hb, AL, AR);
    gat_fused<<<gGat, 256, 0, stream>>>(roff, csr, AL, AR, hb, b2, acc);

    // ---- classifier ----
    classifier<<<gRows32, 256, 0, stream>>>(acc, Wc, bc, out);
}